// Round 1
// 174.417 us; speedup vs baseline: 1.0796x; 1.0796x over previous
//
#include <hip/hip_runtime.h>

// TT-linear, 3 chained bf16 MFMA stages, v2: operand-swapped G2/G3 so that
// every LDS write is a ds_write_b64 and every LDS read is a ds_read_b128,
// with layouts whose bank patterns are minimum-conflict by construction.
//   G1: T1[(n1,r1),(m2,v)] = C0^T @ X-slab    (A=C0^T regs, B=x from global, K=16 pad 32)
//   G2: T2[(n2,r2),n1] per v = C1^T @ T1      (A=C1^T regs, B=T1 LDS b128, K=128)
//   G3: Y[n3,(n1,n2)]  += C2^T @ T2           (A=C2^T regs, B=T2 LDS b128, K=32/slab)
// T1 layout [v][m2][n1][r1]: elem = v*S3 + m2*S2 + n1*8 + r1  (S2=136, S3=2208)
// T2 layout [n2][n1][v][r2]: elem = n2*R2 + n1*R1 + v*8 + r2  (R1=40,  R2=672)
// Bank math (dword bank = (byte/4)%32), all verified by hand:
//   G1 w b64 : bank = 16((c>>2)&1)+4(c&3)+4(q>>1)+2(q&1) -> 4 touches/bank (min)
//   G2 r b128: bank = 4*(((c&7)+q)%8)+16k4               -> 8 touches/bank (min)
//   G2 w b64 : bank = 4*(5c%8)+16(q>>1)+2(q&1)           -> 4 touches/bank (min)
//   G3 r b128: bank = 4*(((5c+q))%8)                     -> 8 touches/bank (min)
// Epilogue: lane holds n3 = 4q..4q+3 contiguous -> float4 store + float4 bias.

typedef __attribute__((ext_vector_type(8))) short bf16x8;
typedef __attribute__((ext_vector_type(4))) float f32x4;

__device__ __forceinline__ unsigned short f2bf(float f) {
    unsigned u = __builtin_bit_cast(unsigned, f);
    u += 0x7FFFu + ((u >> 16) & 1u);   // RNE
    return (unsigned short)(u >> 16);
}

__device__ __forceinline__ unsigned f2bf_pk(float lo, float hi) {
#if __has_builtin(__builtin_amdgcn_cvt_pk_bf16_f32)
    typedef __attribute__((ext_vector_type(2))) __bf16 bf2;
    bf2 r = __builtin_amdgcn_cvt_pk_bf16_f32(lo, hi);
    return __builtin_bit_cast(unsigned, r);
#else
    return (unsigned)f2bf(lo) | ((unsigned)f2bf(hi) << 16);
#endif
}

union BF8 { bf16x8 v; unsigned short s[8]; unsigned u[4]; };
union U2 { uint2 d; unsigned u[2]; };

#define S2 136    // T1 m2-stride (elems)
#define S3 2208   // T1 v-stride  (= 16*S2 + 32 pad; /2 == 16 mod 32)
#define R1 40     // T2 n1-stride (/2 == 20: 5c spread)
#define R2 672    // T2 n2-stride (= 16*R1 + 32 pad; /2 == 16 mod 32)

__global__ __launch_bounds__(512, 4) void tt_mfma3_v2(
    const float* __restrict__ x, const float* __restrict__ c0,
    const float* __restrict__ c1, const float* __restrict__ c2,
    const float* __restrict__ bias, float* __restrict__ out)
{
    __shared__ __align__(16) unsigned short sT1[4 * S3];    // 17664 B
    __shared__ __align__(16) unsigned short sT2[16 * R2];   // 21504 B

    const int tid  = threadIdx.x;
    const int w    = tid >> 6;
    const int lane = tid & 63;
    const int q    = lane >> 4;
    const int c    = lane & 15;
    const int qh   = q >> 1, ql = q & 1;

    // ---- per-stage wave roles (independent; barriers separate stages) ----
    const int ct1  = w & 3;      // G1: col-tile (m2-group of 4)
    const int rtg1 = w >> 2;     // G1: row-tile group (rt = rtg1*4+i, i<4)
    const int rp2  = w & 3;      // G2: rt2-pair (rt2 = rp2*2+i, i<2)
    const int vp2  = w >> 2;     // G2: v-pair  (v = vp2*2+j, j<2)
    // G3: n2 = w*2 + t

    // ---- prologue: register-resident A fragments (once per WG, 4 tokens) ----
    // G1 A = C0^T: row c -> n1 = rt*2+(c>>3), r1 = c&7; k = m1 = q*8+j (q<2)
    BF8 a0[4];
    #pragma unroll
    for (int i = 0; i < 4; ++i) {
        if (q < 2) {
            const int n1 = (rtg1 * 4 + i) * 2 + (c >> 3), r1 = c & 7;
            const float* p = &c0[(q * 8) * 128 + n1 * 8 + r1];
            #pragma unroll
            for (int u = 0; u < 4; ++u)
                a0[i].u[u] = f2bf_pk(p[(2 * u) * 128], p[(2 * u + 1) * 128]);
        } else {
            a0[i].u[0] = a0[i].u[1] = a0[i].u[2] = a0[i].u[3] = 0;
        }
    }
    // G2 A = C1^T: row c -> n2 = rt2*2+(c>>3), r2 = c&7
    //              k = k4*32+q*8+jj -> m2 = k4*4+q, r1 = jj
    BF8 aF[2][4];
    #pragma unroll
    for (int i = 0; i < 2; ++i) {
        const int n2 = (rp2 * 2 + i) * 2 + (c >> 3), r2 = c & 7;
        #pragma unroll
        for (int k4 = 0; k4 < 4; ++k4) {
            const float* p = &c1[(k4 * 4 + q) * 128 + n2 * 8 + r2];
            #pragma unroll
            for (int u = 0; u < 4; ++u)
                aF[i][k4].u[u] = f2bf_pk(p[(2 * u) * 2048], p[(2 * u + 1) * 2048]);
        }
    }
    // G3 A = C2^T per slab: row c = n3; k = q*8+jj -> v = q, r2 = jj
    BF8 a2[4];
    #pragma unroll
    for (int s = 0; s < 4; ++s) {
        const float* p = &c2[(s * 4 + q) * 16 + c];
        #pragma unroll
        for (int u = 0; u < 4; ++u)
            a2[s].u[u] = f2bf_pk(p[(2 * u) * 256], p[(2 * u + 1) * 256]);
    }

    // ---- precomputed per-lane addresses (loop-invariant) ----
    unsigned short* const w1p = &sT1[(c >> 2) * S3 + (ct1 * 4 + (c & 3)) * S2
                                     + (rtg1 * 8 + qh) * 8 + 4 * ql];        // + i*16
    const int xoff = q * 2048 + (ct1 * 4 + (c & 3)) * 16 + (c >> 2);         // + j*256 + s*4
    const unsigned short* const r2p = &sT1[(vp2 * 2) * S3 + q * S2 + c * 8]; // + j*S3 + k4*544
    unsigned short* const w2p = &sT2[(rp2 * 4 + qh) * R2 + c * R1
                                     + vp2 * 16 + 4 * ql];                   // + i*1344 + j*8
    const unsigned short* const r3p = &sT2[(w * 2) * R2 + c * R1 + q * 8];   // + t*R2

    const f32x4 zero = {0.f, 0.f, 0.f, 0.f};

    for (int tok = 0; tok < 4; ++tok) {
        const int b = blockIdx.x * 4 + tok;
        const float* xb = x + (size_t)b * 4096;

        f32x4 acc3[2] = {zero, zero};

        auto G1 = [&](int s) {
            BF8 bx;
            if (q < 2) {
                const float* xp = xb + xoff + s * 4;
                #pragma unroll
                for (int u = 0; u < 4; ++u)
                    bx.u[u] = f2bf_pk(xp[(2 * u) * 256], xp[(2 * u + 1) * 256]);
            } else {
                bx.u[0] = bx.u[1] = bx.u[2] = bx.u[3] = 0;
            }
            #pragma unroll
            for (int i = 0; i < 4; ++i) {
                f32x4 d = __builtin_amdgcn_mfma_f32_16x16x32_bf16(a0[i].v, bx.v, zero, 0, 0, 0);
                U2 t; t.u[0] = f2bf_pk(d[0], d[1]); t.u[1] = f2bf_pk(d[2], d[3]);
                *(uint2*)(w1p + i * 16) = t.d;   // ds_write_b64, conflict-free
            }
        };

        G1(0);
        #pragma unroll
        for (int s = 0; s < 4; ++s) {
            __syncthreads();                      // T1[s] ready
            // ---- G2: per v (j), K=128 chained over k4; B from LDS b128 ----
            f32x4 acc2[2][2] = {{zero, zero}, {zero, zero}};
            #pragma unroll
            for (int k4 = 0; k4 < 4; ++k4) {
                bf16x8 b0 = *(const bf16x8*)(r2p + k4 * 544);
                bf16x8 b1 = *(const bf16x8*)(r2p + S3 + k4 * 544);
                #pragma unroll
                for (int i = 0; i < 2; ++i) {
                    acc2[i][0] = __builtin_amdgcn_mfma_f32_16x16x32_bf16(aF[i][k4].v, b0, acc2[i][0], 0, 0, 0);
                    acc2[i][1] = __builtin_amdgcn_mfma_f32_16x16x32_bf16(aF[i][k4].v, b1, acc2[i][1], 0, 0, 0);
                }
            }
            #pragma unroll
            for (int i = 0; i < 2; ++i) {
                #pragma unroll
                for (int j = 0; j < 2; ++j) {
                    U2 t;
                    t.u[0] = f2bf_pk(acc2[i][j][0], acc2[i][j][1]);
                    t.u[1] = f2bf_pk(acc2[i][j][2], acc2[i][j][3]);
                    *(uint2*)(w2p + i * 1344 + j * 8) = t.d;   // ds_write_b64
                }
            }
            __syncthreads();                      // T2 ready; T1 free
            // ---- G3: acc += C2^T @ T2-slab ----
            {
                bf16x8 b0 = *(const bf16x8*)(r3p);
                bf16x8 b1 = *(const bf16x8*)(r3p + R2);
                acc3[0] = __builtin_amdgcn_mfma_f32_16x16x32_bf16(a2[s].v, b0, acc3[0], 0, 0, 0);
                acc3[1] = __builtin_amdgcn_mfma_f32_16x16x32_bf16(a2[s].v, b1, acc3[1], 0, 0, 0);
            }
            if (s < 3) G1(s + 1);                 // overlaps G3 phase; disjoint buffers
        }

        // ---- epilogue: lane (q,c), tile t: out[c*256 + (2w+t)*16 + 4q + j] ----
        float* outb = out + (size_t)b * 4096;
        #pragma unroll
        for (int t = 0; t < 2; ++t) {
            const int idx = c * 256 + (w * 2 + t) * 16 + 4 * q;
            f32x4 bv = *(const f32x4*)&bias[idx];
            f32x4 o = acc3[t] + bv;
            *(f32x4*)&outb[idx] = o;              // global_store_dwordx4
        }
    }
}

extern "C" void kernel_launch(void* const* d_in, const int* in_sizes, int n_in,
                              void* d_out, int out_size, void* d_ws, size_t ws_size,
                              hipStream_t stream) {
    const float* x    = (const float*)d_in[0];
    const float* c0   = (const float*)d_in[1];  // (1,16,16,8)
    const float* c1   = (const float*)d_in[2];  // (8,16,16,8)
    const float* c2   = (const float*)d_in[3];  // (8,16,16,1)
    const float* bias = (const float*)d_in[4];  // (4096,)
    float* out = (float*)d_out;

    tt_mfma3_v2<<<1024, 512, 0, stream>>>(x, c0, c1, c2, bias, out);
}

// Round 4
// 171.305 us; speedup vs baseline: 1.0993x; 1.0182x over previous
//
#include <hip/hip_runtime.h>

// TT-linear v5 (bisect): v2's hardware-PASSED structure -- 2 barriers/slab,
// single-buffered sT1/sT2, NO swizzle, v2-exact G1/G2/G3 addressing -- with
// exactly three additions from the (failing) v3/v4 delta:
//   (a) 8 tokens/WG, grid 512 (2 WG/CU), prologue amortized 8x
//   (b) x hoisted per-token into packed-bf16 regs via coalesced float4
//       (xpk[s]: B[k=q*8+j][c] = x[m1=q*8+j][m2=ct1*4+(c&3)][m3=(c>>2)*4+s],
//        C2 fragments matched: m3 = q*4 + s)
//   (c) s_setprio(1) around the G2 MFMA cluster
// If this FAILS (absmax ~4.56): the xpk/m3 unit is the v3/v4 bug.
// If it PASSES: the bug is the pipeline/swizzle rewiring; this is the new base.
//   G1: T1[(n1,r1),(m2,v)] = C0^T @ X-slab   (A=C0^T regs, B=xpk; K=16 pad 32)
//   G2: T2[(n2,r2),n1]/v   = C1^T @ T1       (A=C1^T regs, B=T1 LDS b128, K=128)
//   G3: Y[n3,(n1,n2)]     += C2^T @ T2       (A=C2^T regs, B=T2 LDS b128, K=32/slab)
// T1 [v][m2][n1][r1]: elem = v*S3 + m2*S2 + n1*8 + r1  (S2=136, S3=2208)
// T2 [n2][n1][v][r2]: elem = n2*R2 + n1*R1 + v*8 + r2  (R1=40,  R2=672)

typedef __attribute__((ext_vector_type(8))) short bf16x8;
typedef __attribute__((ext_vector_type(4))) float f32x4;

__device__ __forceinline__ unsigned short f2bf(float f) {
    unsigned u = __builtin_bit_cast(unsigned, f);
    u += 0x7FFFu + ((u >> 16) & 1u);   // RNE
    return (unsigned short)(u >> 16);
}

__device__ __forceinline__ unsigned f2bf_pk(float lo, float hi) {
#if __has_builtin(__builtin_amdgcn_cvt_pk_bf16_f32)
    typedef __attribute__((ext_vector_type(2))) __bf16 bf2;
    bf2 r = __builtin_amdgcn_cvt_pk_bf16_f32(lo, hi);
    return __builtin_bit_cast(unsigned, r);
#else
    return (unsigned)f2bf(lo) | ((unsigned)f2bf(hi) << 16);
#endif
}

union BF8 { bf16x8 v; unsigned short s[8]; unsigned u[4]; };
union U2  { uint2 d; unsigned u[2]; };

#define S2 136    // T1 m2-stride (elems)
#define S3 2208   // T1 v-stride  (= 16*S2 + 32 pad)
#define R1 40     // T2 n1-stride
#define R2 672    // T2 n2-stride (= 16*R1 + 32 pad)

#define MFMA32 __builtin_amdgcn_mfma_f32_16x16x32_bf16

__global__ __launch_bounds__(512, 4) void tt_mfma3_v5(
    const float* __restrict__ x, const float* __restrict__ c0,
    const float* __restrict__ c1, const float* __restrict__ c2,
    const float* __restrict__ bias, float* __restrict__ out)
{
    __shared__ __align__(16) unsigned short sT1[4 * S3];    // 17664 B
    __shared__ __align__(16) unsigned short sT2[16 * R2];   // 21504 B

    const int tid  = threadIdx.x;
    const int w    = tid >> 6;
    const int lane = tid & 63;
    const int q    = lane >> 4;
    const int c    = lane & 15;
    const int qh   = q >> 1, ql = q & 1;

    const int ct1  = w & 3;      // G1: col-tile (m2-group of 4)
    const int rtg1 = w >> 2;     // G1: row-tile group (4 tiles)
    const int rp2  = w & 3;      // G2: rt2-pair
    const int vp2  = w >> 2;     // G2: v-pair
    // G3: n2 = w*2 + t

    // ---- loop-invariant LDS pointers (v2 verbatim) ----
    unsigned short* const w1p = &sT1[(c >> 2) * S3 + (ct1 * 4 + (c & 3)) * S2
                                     + (rtg1 * 8 + qh) * 8 + 4 * ql];        // + i*16
    const unsigned short* const r2p = &sT1[(vp2 * 2) * S3 + q * S2 + c * 8]; // + j*S3 + k4*544
    unsigned short* const w2p = &sT2[(rp2 * 4 + qh) * R2 + c * R1
                                     + vp2 * 16 + 4 * ql];                   // + i*1344 + j*8
    const unsigned short* const r3p = &sT2[(w * 2) * R2 + c * R1 + q * 8];   // + t*R2
    const int xcol = ct1 * 64 + (c & 3) * 16 + (c >> 2) * 4;   // m2*16 + v*4

    const f32x4 zero = {0.f, 0.f, 0.f, 0.f};

    // ---- x as packed-bf16 register file: xpk[s] = G1 B-fragment, slab s ----
    BF8 xpk[4];
    #pragma unroll
    for (int s = 0; s < 4; ++s)
        xpk[s].u[0] = xpk[s].u[1] = xpk[s].u[2] = xpk[s].u[3] = 0;

    auto issue_x = [&](int tb) {
        if (q < 2) {
            const float* xb = x + (size_t)(blockIdx.x * 8 + tb) * 4096;
            f32x4 t[8];
            #pragma unroll
            for (int j = 0; j < 8; ++j)
                t[j] = *(const f32x4*)&xb[(q * 8 + j) * 256 + xcol];
            #pragma unroll
            for (int s = 0; s < 4; ++s) {
                #pragma unroll
                for (int u = 0; u < 4; ++u)
                    xpk[s].u[u] = f2bf_pk(t[2 * u][s], t[2 * u + 1][s]);
            }
        }
    };

    issue_x(0);   // latency hidden under the fragment prologue

    // ---- fragment prologue (once per WG, serves 8 tokens) ----
    BF8 a0[4];                    // G1 A (C0^T), K=16 zero-padded: q>=2 rows zero
    #pragma unroll
    for (int i = 0; i < 4; ++i) {
        if (q < 2) {
            const int n1 = (rtg1 * 4 + i) * 2 + (c >> 3), r1 = c & 7;
            const float* p = &c0[(q * 8) * 128 + n1 * 8 + r1];
            #pragma unroll
            for (int u = 0; u < 4; ++u)
                a0[i].u[u] = f2bf_pk(p[(2 * u) * 128], p[(2 * u + 1) * 128]);
        } else {
            a0[i].u[0] = a0[i].u[1] = a0[i].u[2] = a0[i].u[3] = 0;
        }
    }
    BF8 aF[2][4];                 // G2 A (C1^T): k = k4*32+q*8+jj -> (m2,r1)
    #pragma unroll
    for (int i = 0; i < 2; ++i) {
        const int n2 = (rp2 * 2 + i) * 2 + (c >> 3), r2 = c & 7;
        #pragma unroll
        for (int k4 = 0; k4 < 4; ++k4) {
            const float* p = &c1[(k4 * 4 + q) * 128 + n2 * 8 + r2];
            #pragma unroll
            for (int u = 0; u < 4; ++u)
                aF[i][k4].u[u] = f2bf_pk(p[(2 * u) * 2048], p[(2 * u + 1) * 2048]);
        }
    }
    BF8 a2[4];                    // G3 A (C2^T) per slab: k = q*8+j -> (v=q, r2=j)
    #pragma unroll                //   m3 = v*4 + s  (matches xpk's m3 = (c>>2)*4+s)
    for (int s = 0; s < 4; ++s) {
        const float* p = &c2[(q * 4 + s) * 16 + c];
        #pragma unroll
        for (int u = 0; u < 4; ++u)
            a2[s].u[u] = f2bf_pk(p[(2 * u) * 256], p[(2 * u + 1) * 256]);
    }

    // ---- G1 body (v2 structure; B now from xpk) ----
    auto G1 = [&](int s2) {
        #pragma unroll
        for (int i = 0; i < 4; ++i) {
            f32x4 d = MFMA32(a0[i].v, xpk[s2].v, zero, 0, 0, 0);
            U2 t; t.u[0] = f2bf_pk(d[0], d[1]); t.u[1] = f2bf_pk(d[2], d[3]);
            *(uint2*)(w1p + i * 16) = t.d;   // ds_write_b64
        }
    };

    for (int tok = 0; tok < 8; ++tok) {
        const int b = blockIdx.x * 8 + tok;

        f32x4 acc3[2] = {zero, zero};

        G1(0);
        #pragma unroll
        for (int s = 0; s < 4; ++s) {
            __syncthreads();                      // T1[s] ready
            // prefetch next token's x during slab 3's G2/G3 phases
            if (s == 3 && tok < 7) issue_x(tok + 1);
            // ---- G2 (v2 verbatim + setprio): A regs, B = sT1 b128 ----
            f32x4 acc2[2][2] = {{zero, zero}, {zero, zero}};
            __builtin_amdgcn_s_setprio(1);
            #pragma unroll
            for (int k4 = 0; k4 < 4; ++k4) {
                bf16x8 b0 = *(const bf16x8*)(r2p + k4 * 544);
                bf16x8 b1 = *(const bf16x8*)(r2p + S3 + k4 * 544);
                #pragma unroll
                for (int i = 0; i < 2; ++i) {
                    acc2[i][0] = MFMA32(aF[i][k4].v, b0, acc2[i][0], 0, 0, 0);
                    acc2[i][1] = MFMA32(aF[i][k4].v, b1, acc2[i][1], 0, 0, 0);
                }
            }
            __builtin_amdgcn_s_setprio(0);
            #pragma unroll
            for (int i = 0; i < 2; ++i) {
                #pragma unroll
                for (int j = 0; j < 2; ++j) {
                    U2 t;
                    t.u[0] = f2bf_pk(acc2[i][j][0], acc2[i][j][1]);
                    t.u[1] = f2bf_pk(acc2[i][j][2], acc2[i][j][3]);
                    *(uint2*)(w2p + i * 1344 + j * 8) = t.d;   // ds_write_b64
                }
            }
            __syncthreads();                      // T2 ready; T1 free
            // ---- G3 (v2 verbatim) ----
            {
                bf16x8 b0 = *(const bf16x8*)(r3p);
                bf16x8 b1 = *(const bf16x8*)(r3p + R2);
                acc3[0] = MFMA32(a2[s].v, b0, acc3[0], 0, 0, 0);
                acc3[1] = MFMA32(a2[s].v, b1, acc3[1], 0, 0, 0);
            }
            if (s < 3) G1(s + 1);                 // overlaps G3 phase (v2 pattern)
        }

        // ---- epilogue (v2 verbatim) ----
        float* outb = out + (size_t)b * 4096;
        #pragma unroll
        for (int t = 0; t < 2; ++t) {
            const int idx = c * 256 + (w * 2 + t) * 16 + 4 * q;
            f32x4 bv = *(const f32x4*)&bias[idx];
            f32x4 o = acc3[t] + bv;
            *(f32x4*)&outb[idx] = o;   // global_store_dwordx4
        }
    }
}

extern "C" void kernel_launch(void* const* d_in, const int* in_sizes, int n_in,
                              void* d_out, int out_size, void* d_ws, size_t ws_size,
                              hipStream_t stream) {
    const float* x    = (const float*)d_in[0];
    const float* c0   = (const float*)d_in[1];  // (1,16,16,8)
    const float* c1   = (const float*)d_in[2];  // (8,16,16,8)
    const float* c2   = (const float*)d_in[3];  // (8,16,16,1)
    const float* bias = (const float*)d_in[4];  // (4096,)
    float* out = (float*)d_out;

    tt_mfma3_v5<<<512, 512, 0, stream>>>(x, c0, c1, c2, bias, out);
}